// Round 3
// baseline (233.085 us; speedup 1.0000x reference)
//
#include <hip/hip_runtime.h>
#include <math.h>

// Problem constants (from reference)
constexpr int L     = 2048;
constexpr int NH    = 96;
constexpr int MLEN  = 150;
constexpr int NAR   = 148;
constexpr float LAM    = 0.001f;
constexpr float CLIP_K = 4.0f;

constexpr int TM    = 16;          // rows per block (one MFMA row-tile)
constexpr int KQ    = 512;         // k-range per wave (quarter of L)
constexpr int KSTEP = 32;          // k per MFMA step
constexpr int NSTEP = KQ / KSTEP;  // 16

typedef __attribute__((ext_vector_type(8))) short short8;   // 8 bf16 MFMA A/B frag
typedef __attribute__((ext_vector_type(4))) float floatx4;  // MFMA C/D frag

// fp32 -> bf16 round-to-nearest-even
__device__ inline short f2bf(float f) {
    union { float f; unsigned u; } v; v.f = f;
    unsigned r = v.u + 0x7FFFu + ((v.u >> 16) & 1u);
    return (short)(r >> 16);
}

// Pre-kernel: Wt[n][k] = bf16(W[k][n]); 384 KB -> L2-resident.
__global__ __launch_bounds__(256) void wt_kernel(
    const float* __restrict__ W, short* __restrict__ Wt)
{
    int idx = blockIdx.x * 256 + threadIdx.x;   // n*2048 + k
    int n = idx >> 11;
    int k = idx & 2047;
    Wt[idx] = f2bf(W[k * NH + n]);
}

// Barrier-free streaming design (r2 post-mortem: staged version was
// latency/convoy-bound — MfmaUtil 2.6%, VALUBusy 13%, HBM 10%).
//
// 256 threads = 4 waves per 16-row tile; wave e owns k-quarter [e*512, e*512+512).
// NO main-loop LDS, NO main-loop barriers:
//   - A frag loaded straight from x (8 consecutive fp32 of one row; each
//     128B line fetched exactly once — zero over-fetch, no cross-wave reuse
//     exists in a row-split decomposition, so staging buys nothing).
//   - B frag loaded straight from Wt (384 KB, L2-resident; staging an
//     L2-resident operand to LDS is pure overhead — Common-mistake #7).
// Manual 1-step register prefetch; waves free-run, compiler vmcnt-schedules.
// 1024 blocks -> 4 blocks/CU, 16 waves/CU (50% occupancy) for latency hiding.
// One end-of-kernel barrier combines the 4 k-quarter partials via LDS.
//
// MFMA layouts: A[m=lane&15][k=quad*8+j]; B[k=quad*8+j][n=lane&15];
// D col=lane&15, row=quad*4+reg.
__global__ __launch_bounds__(256, 4) void gemm_ar2_kernel(
    const float* __restrict__ x, const short* __restrict__ Wt,
    float* __restrict__ out)
{
    __shared__ float ar[3][6][64][4];    // e=1..3 partial accs, 18 KB,
                                         // [jj][lane][reg]: lane-stride 16B -> conflict-free b128
    __shared__ float s2[3][TM], q2[3][TM];
    __shared__ float Ys[TM][NH + 1];     // +1 pad (stride-97 writes)
    __shared__ float los[TM], his[TM];

    const int t    = threadIdx.x;
    const int lane = t & 63;
    const int e    = t >> 6;            // k quarter
    const int m    = lane & 15;
    const int quad = lane >> 4;
    const int row0 = blockIdx.x * TM;

    const float* pa = x + (size_t)(row0 + m) * L + e * KQ + quad * 8;
    const short* pb[6];
    #pragma unroll
    for (int jj = 0; jj < 6; ++jj)
        pb[jj] = Wt + (size_t)(jj * 16 + m) * L + e * KQ + quad * 8;

    floatx4 acc[6];
    #pragma unroll
    for (int jj = 0; jj < 6; ++jj) acc[jj] = floatx4{0.f, 0.f, 0.f, 0.f};
    float sum = 0.f, sumsq = 0.f;

    // prologue: current-step regs
    float4 ca0 = *(const float4*)(pa);
    float4 ca1 = *(const float4*)(pa + 4);
    short8 cb[6];
    #pragma unroll
    for (int jj = 0; jj < 6; ++jj) cb[jj] = *(const short8*)(pb[jj]);

    #pragma unroll 4
    for (int s = 0; s < NSTEP; ++s) {
        // prefetch next step (last iter: harmless L1-hit reload of current)
        const int off = (s + 1 < NSTEP ? s + 1 : s) * KSTEP;
        float4 na0 = *(const float4*)(pa + off);
        float4 na1 = *(const float4*)(pa + off + 4);
        short8 nb[6];
        #pragma unroll
        for (int jj = 0; jj < 6; ++jj) nb[jj] = *(const short8*)(pb[jj] + off);

        sum  += ((ca0.x + ca0.y) + (ca0.z + ca0.w))
              + ((ca1.x + ca1.y) + (ca1.z + ca1.w));
        sumsq = fmaf(ca0.x, ca0.x, sumsq); sumsq = fmaf(ca0.y, ca0.y, sumsq);
        sumsq = fmaf(ca0.z, ca0.z, sumsq); sumsq = fmaf(ca0.w, ca0.w, sumsq);
        sumsq = fmaf(ca1.x, ca1.x, sumsq); sumsq = fmaf(ca1.y, ca1.y, sumsq);
        sumsq = fmaf(ca1.z, ca1.z, sumsq); sumsq = fmaf(ca1.w, ca1.w, sumsq);

        short8 af;
        af[0] = f2bf(ca0.x); af[1] = f2bf(ca0.y); af[2] = f2bf(ca0.z); af[3] = f2bf(ca0.w);
        af[4] = f2bf(ca1.x); af[5] = f2bf(ca1.y); af[6] = f2bf(ca1.z); af[7] = f2bf(ca1.w);

        #pragma unroll
        for (int jj = 0; jj < 6; ++jj)
            acc[jj] = __builtin_amdgcn_mfma_f32_16x16x32_bf16(af, cb[jj], acc[jj], 0, 0, 0);

        ca0 = na0; ca1 = na1;
        #pragma unroll
        for (int jj = 0; jj < 6; ++jj) cb[jj] = nb[jj];
    }

    // --- combine k-quarters (single barrier in the whole kernel) ---
    if (e > 0) {
        #pragma unroll
        for (int jj = 0; jj < 6; ++jj)
            #pragma unroll
            for (int reg = 0; reg < 4; ++reg)
                ar[e - 1][jj][lane][reg] = acc[jj][reg];
        float su = sum, sq = sumsq;
        su += __shfl_xor(su, 16); su += __shfl_xor(su, 32);
        sq += __shfl_xor(sq, 16); sq += __shfl_xor(sq, 32);
        if (quad == 0) { s2[e - 1][m] = su; q2[e - 1][m] = sq; }
    }
    __syncthreads();

    if (e == 0) {
        #pragma unroll
        for (int q = 0; q < 3; ++q)
            #pragma unroll
            for (int jj = 0; jj < 6; ++jj)
                #pragma unroll
                for (int reg = 0; reg < 4; ++reg)
                    acc[jj][reg] += ar[q][jj][lane][reg];

        sum   += __shfl_xor(sum,   16); sum   += __shfl_xor(sum,   32);
        sumsq += __shfl_xor(sumsq, 16); sumsq += __shfl_xor(sumsq, 32);

        const float* ytail = x + (size_t)(row0 + m) * L + (L - MLEN);
        float A11 = 0.f, A22 = 0.f, A12 = 0.f, b1 = 0.f, b2 = 0.f;
        for (int i = quad; i < NAR; i += 4) {
            float p2v = ytail[i];
            float p1v = ytail[i + 1];
            float Yv  = ytail[i + 2];
            A11 = fmaf(p1v, p1v, A11);
            A22 = fmaf(p2v, p2v, A22);
            A12 = fmaf(p1v, p2v, A12);
            b1  = fmaf(p1v, Yv,  b1);
            b2  = fmaf(p2v, Yv,  b2);
        }
        A11 += __shfl_xor(A11, 16); A11 += __shfl_xor(A11, 32);
        A22 += __shfl_xor(A22, 16); A22 += __shfl_xor(A22, 32);
        A12 += __shfl_xor(A12, 16); A12 += __shfl_xor(A12, 32);
        b1  += __shfl_xor(b1,  16); b1  += __shfl_xor(b1,  32);
        b2  += __shfl_xor(b2,  16); b2  += __shfl_xor(b2,  32);

        if (quad == 0) {                // 16 lanes: one row each
            sum   += s2[0][m] + s2[1][m] + s2[2][m];
            sumsq += q2[0][m] + q2[1][m] + q2[2][m];
            A11 += LAM; A22 += LAM;
            float det = A11 * A22 - A12 * A12;
            float a1c = (b1 * A22 - b2 * A12) / det;
            float a2c = (A11 * b2 - A12 * b1) / det;

            float last = ytail[MLEN - 1];
            float y1 = last;
            float y2 = ytail[MLEN - 2];
            for (int n = 0; n < NH; ++n) {
                float yn = a1c * y1 + a2c * y2;
                Ys[m][n] = yn;
                y2 = y1; y1 = yn;
            }
            float var  = (sumsq - sum * sum * (1.0f / L)) * (1.0f / (L - 1));
            float hstd = fmaxf(sqrtf(fmaxf(var, 0.f)), 1e-6f);
            los[m] = last - CLIP_K * hstd;
            his[m] = last + CLIP_K * hstd;
        }
        // Ys/los/his: written and read by this same wave -> in-order LDS,
        // no barrier needed (e>0 waves are already done).

        #pragma unroll
        for (int reg = 0; reg < 4; ++reg) {
            int rl = quad * 4 + reg;
            float lo = los[rl], hi = his[rl];
            #pragma unroll
            for (int jj = 0; jj < 6; ++jj) {
                int c = jj * 16 + m;
                float v = acc[jj][reg] + Ys[rl][c];
                v = fminf(fmaxf(v, lo), hi);
                out[(size_t)(row0 + rl) * NH + c] = v;
            }
        }
    }
}

extern "C" void kernel_launch(void* const* d_in, const int* in_sizes, int n_in,
                              void* d_out, int out_size, void* d_ws, size_t ws_size,
                              hipStream_t stream) {
    const float* x = (const float*)d_in[0];   // (32,512,2048) fp32
    const float* W = (const float*)d_in[1];   // (2048,96) fp32
    float* out = (float*)d_out;               // (32,512,96) fp32
    short* Wt  = (short*)d_ws;                // 96*2048 bf16 = 384 KB scratch

    wt_kernel<<<dim3((NH * L) / 256), dim3(256), 0, stream>>>(W, Wt);

    const int rows = 32 * 512;                // 16384
    gemm_ar2_kernel<<<dim3(rows / TM), dim3(256), 0, stream>>>(x, Wt, out);
}

// Round 4
// 217.143 us; speedup vs baseline: 1.0734x; 1.0734x over previous
//
#include <hip/hip_runtime.h>
#include <math.h>

// Problem constants (from reference)
constexpr int L     = 2048;
constexpr int NH    = 96;
constexpr int MLEN  = 150;
constexpr int NAR   = 148;
constexpr float LAM    = 0.001f;
constexpr float CLIP_K = 4.0f;

constexpr int TM     = 16;      // rows per block
constexpr int KM     = 64;      // macro K-tile (2 k-halves split across wave pairs)
constexpr int MSTEPS = L / KM;  // 32
constexpr int NBUF   = 4;       // A-ring depth (stage 3 ahead)

typedef __attribute__((ext_vector_type(8))) short short8;   // 8 bf16 MFMA A/B frag
typedef __attribute__((ext_vector_type(4))) float floatx4;  // MFMA C/D frag

// fp32 -> bf16 round-to-nearest-even
__device__ inline short f2bf(float f) {
    union { float f; unsigned u; } v; v.f = f;
    unsigned r = v.u + 0x7FFFu + ((v.u >> 16) & 1u);
    return (short)(r >> 16);
}

// Pre-kernel: Wt[n][k] = bf16(W[k][n]); 384 KB -> L2-resident.
__global__ __launch_bounds__(256) void wt_kernel(
    const float* __restrict__ W, short* __restrict__ Wt)
{
    int idx = blockIdx.x * 256 + threadIdx.x;   // n*2048 + k
    int n = idx >> 11;
    int k = idx & 2047;
    Wt[idx] = f2bf(W[k * NH + n]);
}

// r0-r3 synthesis: every variant was convoy-bound (burst loads, full drain,
// ~1.4-2 TB/s effective with HBM/VALU/MFMA all <15%). This version maximizes
// bytes-in-flight and never drains vmcnt in the main loop:
//   - B (Wt) NOT staged: 384 KB is L2-resident, per-step block working set
//     12 KB is L1-resident. 3 direct short8 loads/wave/step, register
//     double-buffered (24 VGPR).
//   - A staged via global_load_lds (no VGPR cost) into a 4-slot LDS ring,
//     3 steps ahead, with counted s_waitcnt vmcnt + raw s_barrier.
//     vmcnt ledger (order pinned by asm fences, 4 VMEM ops/iter = 3B + 1A,
//     B before A): at top of iter s, ops newer than my A(s) stage =
//     {B(s-1)x3, A(s+1), B(s)x3, A(s+2)} = 8 -> vmcnt(8) forces my A(s)
//     contribution complete pre-barrier, keeps A(s+1),A(s+2),B(s) in flight.
//     Prologue iters (s<2): 5 newer ops -> vmcnt(5). Tail (s>=30): no more
//     stages to count against -> plain __syncthreads.
//   - LDS 22.8 KB -> 4 blocks/CU (grid-capped), 16 waves/CU.
// Wave (g,e): g=wv&1 col-half (48 cols), e=wv>>1 k-half of each 64-k step.
// MFMA layouts: A[m=lane&15][k=quad*8+j]; B[k=quad*8+j][n=lane&15];
// D col=lane&15, row=quad*4+reg.  (Fragment mappings verified r0/r1.)
__global__ __launch_bounds__(256, 4) void gemm_ar2_kernel(
    const float* __restrict__ x, const short* __restrict__ Wt,
    float* __restrict__ out)
{
    __shared__ float As[NBUF][TM * KM];  // 16 KB fp32 ring
    __shared__ float Ys[TM][NH + 1];     // +1 pad (stride-97 writes)
    __shared__ float los[TM], his[TM];
    __shared__ float s2[TM], q2[TM];     // k-half-1 partial stats

    const int t    = threadIdx.x;
    const int lane = t & 63;
    const int wv   = t >> 6;
    const int g    = wv & 1;            // col half
    const int e    = wv >> 1;           // k half
    const int m    = lane & 15;
    const int quad = lane >> 4;
    const int row0 = blockIdx.x * TM;

    // ---- A staging source (1 gload_lds per thread per step) ----
    // thread t stages 16B chunk t of the 16x64 tile: row = t>>4, ch = t&15;
    // within-row: half ch>>3, pos (ch&7)^(row&7)  (XOR swizzle).
    const int rA = t >> 4, chA = t & 15;
    const float* pa = x + (size_t)(row0 + rA) * L
                        + ((chA >> 3) * 32 + ((chA & 7) ^ (rA & 7)) * 4);

    // ---- B direct-load pointers (no staging) ----
    // frag jj: n = g*48 + jj*16 + m; k-chunk = s*64 + e*32 + quad*8.
    const short* pb0 = Wt + (size_t)(g * 48 + m) * L + e * 32 + quad * 8;
    const short* pb1 = pb0 + 16 * (size_t)L;
    const short* pb2 = pb0 + 32 * (size_t)L;

    floatx4 acc[3];
    #pragma unroll
    for (int jj = 0; jj < 3; ++jj) acc[jj] = floatx4{0.f, 0.f, 0.f, 0.f};
    float sum = 0.f, sumsq = 0.f;

    // swizzled A read chunk positions within this wave's k-half
    const int pA0  = (2 * quad)     ^ (m & 7);
    const int pA1  = (2 * quad + 1) ^ (m & 7);
    const int aoff = m * KM + e * 32;

    auto stageA = [&](int buf, int k0) {
        __builtin_amdgcn_global_load_lds(
            (const __attribute__((address_space(1))) unsigned int*)(pa + k0),
            (__attribute__((address_space(3))) unsigned int*)&As[buf][wv * 256], 16, 0, 0);
    };

    // prologue, VMEM order pinned: A(0), B(0)x3, A(1), A(2)
    stageA(0, 0);
    asm volatile("" ::: "memory");
    short8 cb0 = *(const short8*)(pb0);
    short8 cb1 = *(const short8*)(pb1);
    short8 cb2 = *(const short8*)(pb2);
    asm volatile("" ::: "memory");
    stageA(1, KM);
    stageA(2, 2 * KM);

    #pragma unroll 4
    for (int s = 0; s < MSTEPS; ++s) {
        const int cur = s & 3;
        if (s >= MSTEPS - 2) {
            __syncthreads();               // tail: no stages left to count
        } else {
            if (s >= 2) asm volatile("s_waitcnt vmcnt(8)" ::: "memory");
            else        asm volatile("s_waitcnt vmcnt(5)" ::: "memory");
            __builtin_amdgcn_s_barrier();
        }
        __builtin_amdgcn_sched_barrier(0); // pin: nothing crosses the barrier

        // B prefetch for s+1 (pinned BEFORE the A-stage; last iter: L1 reload)
        const int off = (s + 1 < MSTEPS ? s + 1 : s) * KM;
        short8 nb0 = *(const short8*)(pb0 + off);
        short8 nb1 = *(const short8*)(pb1 + off);
        short8 nb2 = *(const short8*)(pb2 + off);
        asm volatile("" ::: "memory");
        if (s + 3 < MSTEPS) stageA((s + 3) & 3, (s + 3) * KM);

        float4 f0 = *(const float4*)&As[cur][aoff + pA0 * 4];
        float4 f1 = *(const float4*)&As[cur][aoff + pA1 * 4];

        if (g == 0) {   // waves 0,2: each covers its k-half of all 16 rows
            sum  += ((f0.x + f0.y) + (f0.z + f0.w))
                  + ((f1.x + f1.y) + (f1.z + f1.w));
            sumsq = fmaf(f0.x, f0.x, sumsq); sumsq = fmaf(f0.y, f0.y, sumsq);
            sumsq = fmaf(f0.z, f0.z, sumsq); sumsq = fmaf(f0.w, f0.w, sumsq);
            sumsq = fmaf(f1.x, f1.x, sumsq); sumsq = fmaf(f1.y, f1.y, sumsq);
            sumsq = fmaf(f1.z, f1.z, sumsq); sumsq = fmaf(f1.w, f1.w, sumsq);
        }

        short8 af;
        af[0] = f2bf(f0.x); af[1] = f2bf(f0.y); af[2] = f2bf(f0.z); af[3] = f2bf(f0.w);
        af[4] = f2bf(f1.x); af[5] = f2bf(f1.y); af[6] = f2bf(f1.z); af[7] = f2bf(f1.w);

        acc[0] = __builtin_amdgcn_mfma_f32_16x16x32_bf16(af, cb0, acc[0], 0, 0, 0);
        acc[1] = __builtin_amdgcn_mfma_f32_16x16x32_bf16(af, cb1, acc[1], 0, 0, 0);
        acc[2] = __builtin_amdgcn_mfma_f32_16x16x32_bf16(af, cb2, acc[2], 0, 0, 0);

        cb0 = nb0; cb1 = nb1; cb2 = nb2;
    }

    // --- k-half reduction. Reuse As[0..] as scratch: the s>=30 __syncthreads
    //     drained all gload_lds; iter-31 readers touch slot 3 only (disjoint
    //     from ar's 6 KB in slots 0-1). ---
    float* ar = (float*)&As[0][0];    // 2 col-halves x 64 lanes x 12 = 6 KB
    if (e == 1) {
        #pragma unroll
        for (int jj = 0; jj < 3; ++jj)
            #pragma unroll
            for (int reg = 0; reg < 4; ++reg)
                ar[(g * 64 + lane) * 12 + jj * 4 + reg] = acc[jj][reg];
        if (g == 0) {   // wave 2: publish k-half-1 stats
            float su = sum, sq = sumsq;
            su += __shfl_xor(su, 16); su += __shfl_xor(su, 32);
            sq += __shfl_xor(sq, 16); sq += __shfl_xor(sq, 32);
            if (quad == 0) { s2[m] = su; q2[m] = sq; }
        }
    }
    __syncthreads();

    if (e == 0) {
        #pragma unroll
        for (int jj = 0; jj < 3; ++jj)
            #pragma unroll
            for (int reg = 0; reg < 4; ++reg)
                acc[jj][reg] += ar[(g * 64 + lane) * 12 + jj * 4 + reg];

        if (g == 0) {   // wave 0: stats + AR2 + clip bounds for all 16 rows
            sum   += __shfl_xor(sum,   16); sum   += __shfl_xor(sum,   32);
            sumsq += __shfl_xor(sumsq, 16); sumsq += __shfl_xor(sumsq, 32);

            const float* ytail = x + (size_t)(row0 + m) * L + (L - MLEN);
            float A11 = 0.f, A22 = 0.f, A12 = 0.f, b1 = 0.f, b2 = 0.f;
            for (int i = quad; i < NAR; i += 4) {
                float p2v = ytail[i];
                float p1v = ytail[i + 1];
                float Yv  = ytail[i + 2];
                A11 = fmaf(p1v, p1v, A11);
                A22 = fmaf(p2v, p2v, A22);
                A12 = fmaf(p1v, p2v, A12);
                b1  = fmaf(p1v, Yv,  b1);
                b2  = fmaf(p2v, Yv,  b2);
            }
            A11 += __shfl_xor(A11, 16); A11 += __shfl_xor(A11, 32);
            A22 += __shfl_xor(A22, 16); A22 += __shfl_xor(A22, 32);
            A12 += __shfl_xor(A12, 16); A12 += __shfl_xor(A12, 32);
            b1  += __shfl_xor(b1,  16); b1  += __shfl_xor(b1,  32);
            b2  += __shfl_xor(b2,  16); b2  += __shfl_xor(b2,  32);

            if (quad == 0) {            // 16 lanes: one row each
                sum   += s2[m];
                sumsq += q2[m];
                A11 += LAM; A22 += LAM;
                float det = A11 * A22 - A12 * A12;
                float a1c = (b1 * A22 - b2 * A12) / det;
                float a2c = (A11 * b2 - A12 * b1) / det;

                float last = ytail[MLEN - 1];
                float y1 = last;
                float y2 = ytail[MLEN - 2];
                for (int n = 0; n < NH; ++n) {
                    float yn = a1c * y1 + a2c * y2;
                    Ys[m][n] = yn;
                    y2 = y1; y1 = yn;
                }
                float var  = (sumsq - sum * sum * (1.0f / L)) * (1.0f / (L - 1));
                float hstd = fmaxf(sqrtf(fmaxf(var, 0.f)), 1e-6f);
                los[m] = last - CLIP_K * hstd;
                his[m] = last + CLIP_K * hstd;
            }
        }
    }
    __syncthreads();

    // --- epilogue: waves 0,1 store the 16x96 tile (wave g: 48-col half) ---
    if (e == 0) {
        #pragma unroll
        for (int reg = 0; reg < 4; ++reg) {
            int rl = quad * 4 + reg;
            float lo = los[rl], hi = his[rl];
            #pragma unroll
            for (int jj = 0; jj < 3; ++jj) {
                int c = (3 * g + jj) * 16 + m;
                float v = acc[jj][reg] + Ys[rl][c];
                v = fminf(fmaxf(v, lo), hi);
                out[(size_t)(row0 + rl) * NH + c] = v;
            }
        }
    }
}

extern "C" void kernel_launch(void* const* d_in, const int* in_sizes, int n_in,
                              void* d_out, int out_size, void* d_ws, size_t ws_size,
                              hipStream_t stream) {
    const float* x = (const float*)d_in[0];   // (32,512,2048) fp32
    const float* W = (const float*)d_in[1];   // (2048,96) fp32
    float* out = (float*)d_out;               // (32,512,96) fp32
    short* Wt  = (short*)d_ws;                // 96*2048 bf16 = 384 KB scratch

    wt_kernel<<<dim3((NH * L) / 256), dim3(256), 0, stream>>>(W, Wt);

    const int rows = 32 * 512;                // 16384
    gemm_ar2_kernel<<<dim3(rows / TM), dim3(256), 0, stream>>>(x, Wt, out);
}